// Round 1
// baseline (803.638 us; speedup 1.0000x reference)
//
#include <hip/hip_runtime.h>
#include <hip/hip_bf16.h>

#define TOK   8192      // B*T
#define NVAR  32
#define DDIM  64
#define HDIM  128
#define CDIM  64
#define ND    2048      // N*D
#define LN_EPS 1e-5f

__device__ __forceinline__ float bf2f(unsigned short u) {
    unsigned int x = ((unsigned int)u) << 16;
    return __uint_as_float(x);
}
__device__ __forceinline__ unsigned short f2bf(float f) {
    unsigned int x = __float_as_uint(f);
    unsigned int r = (x + 0x7fffu + ((x >> 16) & 1u)) >> 16;
    return (unsigned short)r;
}
__device__ __forceinline__ float elu_f(float x) {
    return x > 0.f ? x : (__expf(x) - 1.f);
}
__device__ __forceinline__ float sigm_f(float x) {
    return 1.f / (1.f + __expf(-x));
}

// ---------------- ctx_proj = context @ f_Wc  [64,128] ----------------
__global__ void k_ctx(const float* __restrict__ ctx, const float* __restrict__ Wc,
                      float* __restrict__ ctxp) {
    int b = blockIdx.x, h = threadIdx.x;
    __shared__ float cs[CDIM];
    if (threadIdx.x < CDIM) cs[threadIdx.x] = ctx[b * CDIM + threadIdx.x];
    __syncthreads();
    float acc = 0.f;
#pragma unroll
    for (int c = 0; c < CDIM; ++c) acc += cs[c] * Wc[c * HDIM + h];
    ctxp[b * HDIM + h] = acc;
}

// ---------------- h1 = elu(flat @ f_W1 + b1 + ctxp)  [8192,128] ----------------
// tile: 32 tokens x 128 cols, KT=32. grid 256, block 256.
__global__ __launch_bounds__(256) void k_h1(const float* __restrict__ emb,
        const float* __restrict__ W1, const float* __restrict__ b1,
        const float* __restrict__ ctxp, float* __restrict__ h1) {
    __shared__ float As[32][36];
    __shared__ float Bs[32][128];
    int tid = threadIdx.x;
    int tok0 = blockIdx.x * 32;
    int cg = tid & 31, tg = tid >> 5;   // cols cg*4.., tokens tg*4..
    float acc[4][4] = {};
    for (int k0 = 0; k0 < ND; k0 += 32) {
        {
            int row = tid >> 3, c4 = (tid & 7) * 4;
            *(float4*)&As[row][c4] = *(const float4*)(emb + (size_t)(tok0 + row) * ND + k0 + c4);
        }
#pragma unroll
        for (int r = 0; r < 4; ++r) {
            int idx = tid + 256 * r;
            int row = idx >> 5, c4 = (idx & 31) * 4;
            *(float4*)&Bs[row][c4] = *(const float4*)(W1 + (size_t)(k0 + row) * HDIM + c4);
        }
        __syncthreads();
#pragma unroll
        for (int kk = 0; kk < 32; ++kk) {
            float4 bv = *(const float4*)&Bs[kk][cg * 4];
#pragma unroll
            for (int i = 0; i < 4; ++i) {
                float a = As[tg * 4 + i][kk];
                acc[i][0] += a * bv.x; acc[i][1] += a * bv.y;
                acc[i][2] += a * bv.z; acc[i][3] += a * bv.w;
            }
        }
        __syncthreads();
    }
    float4 bb = *(const float4*)(b1 + cg * 4);
#pragma unroll
    for (int i = 0; i < 4; ++i) {
        int tok = tok0 + tg * 4 + i;
        int b = tok >> 7;
        float4 cc = *(const float4*)(ctxp + b * HDIM + cg * 4);
        float4 o;
        o.x = elu_f(acc[i][0] + bb.x + cc.x);
        o.y = elu_f(acc[i][1] + bb.y + cc.y);
        o.z = elu_f(acc[i][2] + bb.z + cc.z);
        o.w = elu_f(acc[i][3] + bb.w + cc.w);
        *(float4*)(h1 + (size_t)tok * HDIM + cg * 4) = o;
    }
}

// ---------------- skip = flat @ f_Wskip + bskip  [8192,32] ----------------
// tile: 64 tokens x 32 cols. grid 128, block 256.
__global__ __launch_bounds__(256) void k_skip(const float* __restrict__ emb,
        const float* __restrict__ Wsk, const float* __restrict__ bsk,
        float* __restrict__ skip) {
    __shared__ float As[64][36];
    __shared__ float Bs[32][36];
    int tid = threadIdx.x;
    int tok0 = blockIdx.x * 64;
    int cg = tid & 7, tg = tid >> 3;    // cols cg*4.., tokens tg*2..
    float acc[2][4] = {};
    for (int k0 = 0; k0 < ND; k0 += 32) {
#pragma unroll
        for (int r = 0; r < 2; ++r) {
            int idx = tid + 256 * r;
            int row = idx >> 3, c4 = (idx & 7) * 4;
            *(float4*)&As[row][c4] = *(const float4*)(emb + (size_t)(tok0 + row) * ND + k0 + c4);
        }
        {
            int row = tid >> 3, c4 = (tid & 7) * 4;
            *(float4*)&Bs[row][c4] = *(const float4*)(Wsk + (size_t)(k0 + row) * NVAR + c4);
        }
        __syncthreads();
#pragma unroll
        for (int kk = 0; kk < 32; ++kk) {
            float4 bv = *(const float4*)&Bs[kk][cg * 4];
#pragma unroll
            for (int i = 0; i < 2; ++i) {
                float a = As[tg * 2 + i][kk];
                acc[i][0] += a * bv.x; acc[i][1] += a * bv.y;
                acc[i][2] += a * bv.z; acc[i][3] += a * bv.w;
            }
        }
        __syncthreads();
    }
    float4 bb = *(const float4*)(bsk + cg * 4);
#pragma unroll
    for (int i = 0; i < 2; ++i) {
        int tok = tok0 + tg * 2 + i;
        float4 o;
        o.x = acc[i][0] + bb.x; o.y = acc[i][1] + bb.y;
        o.z = acc[i][2] + bb.z; o.w = acc[i][3] + bb.w;
        *(float4*)(skip + (size_t)tok * NVAR + cg * 4) = o;
    }
}

// ---------------- selection: h2,g,glu,LN,softmax -> weights [8192,32] ----------------
__global__ __launch_bounds__(128) void k_sel(const float* __restrict__ h1,
        const float* __restrict__ skip,
        const float* __restrict__ W2, const float* __restrict__ b2,
        const float* __restrict__ Wg, const float* __restrict__ bg,
        const float* __restrict__ fg, const float* __restrict__ fb,
        float* __restrict__ wout) {
    int tok = blockIdx.x, t = threadIdx.x;
    __shared__ float hb[HDIM], h2b[HDIM], gb[64];
    hb[t] = h1[(size_t)tok * HDIM + t];
    __syncthreads();
    float acc = b2[t];
#pragma unroll 8
    for (int k = 0; k < HDIM; ++k) acc += hb[k] * W2[k * HDIM + t];
    h2b[t] = acc;
    __syncthreads();
    if (t < 64) {
        float g = bg[t];
#pragma unroll 8
        for (int k = 0; k < HDIM; ++k) g += h2b[k] * Wg[k * 64 + t];
        gb[t] = g;
    }
    __syncthreads();
    if (t < 32) {
        float a = gb[t], b = gb[t + 32];
        float val = a * sigm_f(b) + skip[(size_t)tok * NVAR + t];
        float s = val, q = val * val;
#pragma unroll
        for (int m = 16; m >= 1; m >>= 1) { s += __shfl_xor(s, m, 32); q += __shfl_xor(q, m, 32); }
        float mean = s * (1.f / 32.f);
        float var = q * (1.f / 32.f) - mean * mean;
        float logit = (val - mean) * rsqrtf(var + LN_EPS) * fg[t] + fb[t];
        float mx = logit;
#pragma unroll
        for (int m = 16; m >= 1; m >>= 1) mx = fmaxf(mx, __shfl_xor(mx, m, 32));
        float e = __expf(logit - mx);
        float se = e;
#pragma unroll
        for (int m = 16; m >= 1; m >>= 1) se += __shfl_xor(se, m, 32);
        wout[(size_t)tok * NVAR + t] = e / se;
    }
}

// ---------------- per-variable GRNs + weighted accumulate ----------------
// grid (128 token-tiles, 32 n), block 256, TT=64 tokens/tile.
// LDS pool (64KB, ushort units):
//   VSB  [64][128] @ 0      (live ph1-3)
//   VH2B [64][128] @ 8192   (live ph2-3)
//   VHB  [64][128] @ 16384  (live ph1-2)
//   EB   [64][68]  @ 24576  (live ph1)
//   VG   [64][256] @ 16384  (live ph3; overlaps dead VHB+EB)
#define TT 64
__global__ __launch_bounds__(256) void k_var(const float* __restrict__ emb,
        const float* __restrict__ vW1, const float* __restrict__ vb1,
        const float* __restrict__ vWsk, const float* __restrict__ vbsk,
        const float* __restrict__ vW2, const float* __restrict__ vb2,
        const float* __restrict__ vWg, const float* __restrict__ vbg,
        const float* __restrict__ gam, const float* __restrict__ bet,
        const float* __restrict__ wsel, float* __restrict__ outp) {
    __shared__ unsigned short pool[32768];
    unsigned short* VSB  = pool;
    unsigned short* VH2B = pool + 8192;
    unsigned short* VHB  = pool + 16384;
    unsigned short* EB   = pool + 24576;
    unsigned short* VG   = pool + 16384;

    int tid = threadIdx.x;
    int tok0 = blockIdx.x * TT;
    int n = blockIdx.y;

    // ---- stage embedding slice [64 tokens][64] as bf16 ----
#pragma unroll
    for (int r = 0; r < 4; ++r) {
        int idx = tid + 256 * r;          // 0..1023
        int row = idx >> 4, c4 = (idx & 15) * 4;
        float4 v = *(const float4*)(emb + ((size_t)(tok0 + row) * NVAR + n) * DDIM + c4);
        unsigned short* p = EB + row * 68 + c4;
        p[0] = f2bf(v.x); p[1] = f2bf(v.y); p[2] = f2bf(v.z); p[3] = f2bf(v.w);
    }
    __syncthreads();

    int cg = tid & 31, tg = tid >> 5;     // cols cg*4.., token-group tg (8 tokens each)

    // ---- phase 1: vh = elu(E@W1+b1), vskip = E@Wsk+bsk ----
    {
        float a1[8][4] = {}; float a2[8][4] = {};
        const float* w1p = vW1 + (size_t)n * DDIM * HDIM + cg * 4;
        const float* wsp = vWsk + (size_t)n * DDIM * HDIM + cg * 4;
#pragma unroll 2
        for (int k = 0; k < DDIM; ++k) {
            float4 w1 = *(const float4*)(w1p + (size_t)k * HDIM);
            float4 ws = *(const float4*)(wsp + (size_t)k * HDIM);
#pragma unroll
            for (int i = 0; i < 8; ++i) {
                float a = bf2f(EB[(tg * 8 + i) * 68 + k]);
                a1[i][0] += a * w1.x; a1[i][1] += a * w1.y; a1[i][2] += a * w1.z; a1[i][3] += a * w1.w;
                a2[i][0] += a * ws.x; a2[i][1] += a * ws.y; a2[i][2] += a * ws.z; a2[i][3] += a * ws.w;
            }
        }
        float4 bb1 = *(const float4*)(vb1 + n * HDIM + cg * 4);
        float4 bbs = *(const float4*)(vbsk + n * HDIM + cg * 4);
#pragma unroll
        for (int i = 0; i < 8; ++i) {
            int tr = tg * 8 + i;
            ushort4 hv, sv;
            hv.x = f2bf(elu_f(a1[i][0] + bb1.x));
            hv.y = f2bf(elu_f(a1[i][1] + bb1.y));
            hv.z = f2bf(elu_f(a1[i][2] + bb1.z));
            hv.w = f2bf(elu_f(a1[i][3] + bb1.w));
            sv.x = f2bf(a2[i][0] + bbs.x);
            sv.y = f2bf(a2[i][1] + bbs.y);
            sv.z = f2bf(a2[i][2] + bbs.z);
            sv.w = f2bf(a2[i][3] + bbs.w);
            *(ushort4*)(VHB + tr * HDIM + cg * 4) = hv;
            *(ushort4*)(VSB + tr * HDIM + cg * 4) = sv;
        }
    }
    __syncthreads();

    // ---- phase 2: vh2 = vh@W2+b2 ----
    {
        float a3[8][4] = {};
        const float* w2p = vW2 + (size_t)n * HDIM * HDIM + cg * 4;
#pragma unroll 2
        for (int k = 0; k < HDIM; ++k) {
            float4 w2 = *(const float4*)(w2p + (size_t)k * HDIM);
#pragma unroll
            for (int i = 0; i < 8; ++i) {
                float a = bf2f(VHB[(tg * 8 + i) * HDIM + k]);
                a3[i][0] += a * w2.x; a3[i][1] += a * w2.y; a3[i][2] += a * w2.z; a3[i][3] += a * w2.w;
            }
        }
        float4 bb2 = *(const float4*)(vb2 + n * HDIM + cg * 4);
#pragma unroll
        for (int i = 0; i < 8; ++i) {
            int tr = tg * 8 + i;
            ushort4 hv;
            hv.x = f2bf(a3[i][0] + bb2.x);
            hv.y = f2bf(a3[i][1] + bb2.y);
            hv.z = f2bf(a3[i][2] + bb2.z);
            hv.w = f2bf(a3[i][3] + bb2.w);
            *(ushort4*)(VH2B + tr * HDIM + cg * 4) = hv;
        }
    }
    __syncthreads();

    // ---- phase 3: vg = vh2@Wg+bg  (256 cols) ----
    {
        int cg2 = tid & 63, tg2 = tid >> 6;   // cols cg2*4.., 4 groups x 16 tokens
        float a4[16][4] = {};
        const float* wgp = vWg + (size_t)n * HDIM * 256 + cg2 * 4;
#pragma unroll 2
        for (int k = 0; k < HDIM; ++k) {
            float4 wg4 = *(const float4*)(wgp + (size_t)k * 256);
#pragma unroll
            for (int i = 0; i < 16; ++i) {
                float a = bf2f(VH2B[(tg2 * 16 + i) * HDIM + k]);
                a4[i][0] += a * wg4.x; a4[i][1] += a * wg4.y; a4[i][2] += a * wg4.z; a4[i][3] += a * wg4.w;
            }
        }
        float4 bbg = *(const float4*)(vbg + n * 256 + cg2 * 4);
#pragma unroll
        for (int i = 0; i < 16; ++i) {
            int tr = tg2 * 16 + i;
            ushort4 hv;
            hv.x = f2bf(a4[i][0] + bbg.x);
            hv.y = f2bf(a4[i][1] + bbg.y);
            hv.z = f2bf(a4[i][2] + bbg.z);
            hv.w = f2bf(a4[i][3] + bbg.w);
            *(ushort4*)(VG + tr * 256 + cg2 * 4) = hv;
        }
    }
    __syncthreads();

    // ---- combine: glu + vskip, LN, *gamma+beta, *weight, atomic accumulate ----
    {
        int lane = tid & 63, w = tid >> 6;
        int c0 = lane * 2;
        float g0 = gam[n * HDIM + c0], g1 = gam[n * HDIM + c0 + 1];
        float be0 = bet[n * HDIM + c0], be1 = bet[n * HDIM + c0 + 1];
#pragma unroll 2
        for (int i = 0; i < 16; ++i) {
            int tr = w * 16 + i;
            float a0 = bf2f(VG[tr * 256 + c0]);
            float a1v = bf2f(VG[tr * 256 + c0 + 1]);
            float b0 = bf2f(VG[tr * 256 + 128 + c0]);
            float b1v = bf2f(VG[tr * 256 + 128 + c0 + 1]);
            float s0 = bf2f(VSB[tr * HDIM + c0]);
            float s1 = bf2f(VSB[tr * HDIM + c0 + 1]);
            float v0 = a0 * sigm_f(b0) + s0;
            float v1 = a1v * sigm_f(b1v) + s1;
            float s = v0 + v1, q = v0 * v0 + v1 * v1;
#pragma unroll
            for (int m = 32; m >= 1; m >>= 1) { s += __shfl_xor(s, m); q += __shfl_xor(q, m); }
            float mean = s * (1.f / 128.f);
            float var = q * (1.f / 128.f) - mean * mean;
            float inv = rsqrtf(var + LN_EPS);
            float t0 = (v0 - mean) * inv * g0 + be0;
            float t1 = (v1 - mean) * inv * g1 + be1;
            float wgt = wsel[(size_t)(tok0 + tr) * NVAR + n];
            float* po = outp + (size_t)(tok0 + tr) * HDIM + c0;
            atomicAdd(po, wgt * t0);
            atomicAdd(po + 1, wgt * t1);
        }
    }
}

extern "C" void kernel_launch(void* const* d_in, const int* in_sizes, int n_in,
                              void* d_out, int out_size, void* d_ws, size_t ws_size,
                              hipStream_t stream) {
    const float* emb  = (const float*)d_in[0];
    const float* ctx  = (const float*)d_in[1];
    const float* fWsk = (const float*)d_in[2];
    const float* fbsk = (const float*)d_in[3];
    const float* fW1  = (const float*)d_in[4];
    const float* fb1  = (const float*)d_in[5];
    const float* fWc  = (const float*)d_in[6];
    const float* fW2  = (const float*)d_in[7];
    const float* fb2  = (const float*)d_in[8];
    const float* fWg  = (const float*)d_in[9];
    const float* fbg  = (const float*)d_in[10];
    const float* fg   = (const float*)d_in[11];
    const float* fb   = (const float*)d_in[12];
    const float* vWsk = (const float*)d_in[13];
    const float* vbsk = (const float*)d_in[14];
    const float* vW1  = (const float*)d_in[15];
    const float* vb1  = (const float*)d_in[16];
    const float* vW2  = (const float*)d_in[17];
    const float* vb2  = (const float*)d_in[18];
    const float* vWg  = (const float*)d_in[19];
    const float* vbg  = (const float*)d_in[20];
    const float* vgam = (const float*)d_in[21];
    const float* vbet = (const float*)d_in[22];

    float* outp = (float*)d_out;                       // [8192][128]
    float* wout = outp + (size_t)TOK * HDIM;           // [8192][32]
    float* ctxp = (float*)d_ws;                        // [64][128]
    float* h1   = ctxp + 64 * HDIM;                    // [8192][128]
    float* skip = h1 + (size_t)TOK * HDIM;             // [8192][32]

    hipMemsetAsync(d_out, 0, (size_t)TOK * HDIM * sizeof(float), stream);
    k_ctx<<<64, 128, 0, stream>>>(ctx, fWc, ctxp);
    k_h1<<<256, 256, 0, stream>>>(emb, fW1, fb1, ctxp, h1);
    k_skip<<<128, 256, 0, stream>>>(emb, fWsk, fbsk, skip);
    k_sel<<<TOK, 128, 0, stream>>>(h1, skip, fW2, fb2, fWg, fbg, fg, fb, wout);
    k_var<<<dim3(TOK / TT, NVAR), 256, 0, stream>>>(emb, vW1, vb1, vWsk, vbsk,
                                                    vW2, vb2, vWg, vbg, vgam, vbet,
                                                    wout, outp);
}

// Round 2
// 463.421 us; speedup vs baseline: 1.7341x; 1.7341x over previous
//
#include <hip/hip_runtime.h>
#include <hip/hip_bf16.h>

#define TOK   8192      // B*T
#define NVAR  32
#define DDIM  64
#define HDIM  128
#define CDIM  64
#define ND    2048      // N*D
#define LN_EPS 1e-5f
#define TT 64

typedef float f32x4 __attribute__((ext_vector_type(4)));
typedef short s16x8 __attribute__((ext_vector_type(8)));
typedef unsigned short u16x8 __attribute__((ext_vector_type(8)));

__device__ __forceinline__ float bf2f(unsigned short u) {
    unsigned int x = ((unsigned int)u) << 16;
    return __uint_as_float(x);
}
__device__ __forceinline__ unsigned short f2bf(float f) {
    unsigned int x = __float_as_uint(f);
    unsigned int r = (x + 0x7fffu + ((x >> 16) & 1u)) >> 16;
    return (unsigned short)r;
}
__device__ __forceinline__ float elu_f(float x) {
    return x > 0.f ? x : (__expf(x) - 1.f);
}
__device__ __forceinline__ float sigm_f(float x) {
    return 1.f / (1.f + __expf(-x));
}
__device__ __forceinline__ s16x8 frag_ld(const unsigned short* p) {
    return __builtin_bit_cast(s16x8, *(const u16x8*)p);
}
__device__ __forceinline__ f32x4 mfma_bf16(s16x8 a, s16x8 b, f32x4 c) {
    return __builtin_amdgcn_mfma_f32_16x16x32_bf16(a, b, c, 0, 0, 0);
}

// ---------------- pack weight W[n][K][N] fp32 -> fragment-major bf16 ----------------
// out[n][ks][nf][lane][8]: element = W[n][ks*32 + (lane>>4)*8 + j][nf*16 + (lane&15)]
__global__ void k_pack(const float* __restrict__ W, unsigned short* __restrict__ out,
                       int K, int N) {
    int NF = N >> 4;
    int bx = blockIdx.x;              // ks*NF + nf
    int ks = bx / NF, nf = bx - ks * NF;
    int n = blockIdx.y;
    int lane = threadIdx.x;
    int col = nf * 16 + (lane & 15);
    int k0 = ks * 32 + (lane >> 4) * 8;
    const float* src = W + (size_t)n * K * N + (size_t)k0 * N + col;
    unsigned short* dst = out + (size_t)n * K * N + ((size_t)bx * 64 + lane) * 8;
    unsigned short v[8];
#pragma unroll
    for (int j = 0; j < 8; ++j) v[j] = f2bf(src[(size_t)j * N]);
    *(u16x8*)dst = *(const u16x8*)v;
}

// ---------------- ctx_proj = context @ f_Wc  [64,128] ----------------
__global__ void k_ctx(const float* __restrict__ ctx, const float* __restrict__ Wc,
                      float* __restrict__ ctxp) {
    int b = blockIdx.x, h = threadIdx.x;
    __shared__ float cs[CDIM];
    if (threadIdx.x < CDIM) cs[threadIdx.x] = ctx[b * CDIM + threadIdx.x];
    __syncthreads();
    float acc = 0.f;
#pragma unroll
    for (int c = 0; c < CDIM; ++c) acc += cs[c] * Wc[c * HDIM + h];
    ctxp[b * HDIM + h] = acc;
}

// ---------------- h1 = elu(flat @ f_W1 + b1 + ctxp)  [8192,128] ----------------
__global__ __launch_bounds__(256) void k_h1(const float* __restrict__ emb,
        const float* __restrict__ W1, const float* __restrict__ b1,
        const float* __restrict__ ctxp, float* __restrict__ h1) {
    __shared__ float As[32][36];
    __shared__ float Bs[32][128];
    int tid = threadIdx.x;
    int tok0 = blockIdx.x * 32;
    int cg = tid & 31, tg = tid >> 5;
    float acc[4][4] = {};
    for (int k0 = 0; k0 < ND; k0 += 32) {
        {
            int row = tid >> 3, c4 = (tid & 7) * 4;
            *(float4*)&As[row][c4] = *(const float4*)(emb + (size_t)(tok0 + row) * ND + k0 + c4);
        }
#pragma unroll
        for (int r = 0; r < 4; ++r) {
            int idx = tid + 256 * r;
            int row = idx >> 5, c4 = (idx & 31) * 4;
            *(float4*)&Bs[row][c4] = *(const float4*)(W1 + (size_t)(k0 + row) * HDIM + c4);
        }
        __syncthreads();
#pragma unroll
        for (int kk = 0; kk < 32; ++kk) {
            float4 bv = *(const float4*)&Bs[kk][cg * 4];
#pragma unroll
            for (int i = 0; i < 4; ++i) {
                float a = As[tg * 4 + i][kk];
                acc[i][0] += a * bv.x; acc[i][1] += a * bv.y;
                acc[i][2] += a * bv.z; acc[i][3] += a * bv.w;
            }
        }
        __syncthreads();
    }
    float4 bb = *(const float4*)(b1 + cg * 4);
#pragma unroll
    for (int i = 0; i < 4; ++i) {
        int tok = tok0 + tg * 4 + i;
        int b = tok >> 7;
        float4 cc = *(const float4*)(ctxp + b * HDIM + cg * 4);
        float4 o;
        o.x = elu_f(acc[i][0] + bb.x + cc.x);
        o.y = elu_f(acc[i][1] + bb.y + cc.y);
        o.z = elu_f(acc[i][2] + bb.z + cc.z);
        o.w = elu_f(acc[i][3] + bb.w + cc.w);
        *(float4*)(h1 + (size_t)tok * HDIM + cg * 4) = o;
    }
}

// ---------------- skip = flat @ f_Wskip + bskip  [8192,32] ----------------
__global__ __launch_bounds__(256) void k_skip(const float* __restrict__ emb,
        const float* __restrict__ Wsk, const float* __restrict__ bsk,
        float* __restrict__ skip) {
    __shared__ float As[64][36];
    __shared__ float Bs[32][36];
    int tid = threadIdx.x;
    int tok0 = blockIdx.x * 64;
    int cg = tid & 7, tg = tid >> 3;
    float acc[2][4] = {};
    for (int k0 = 0; k0 < ND; k0 += 32) {
#pragma unroll
        for (int r = 0; r < 2; ++r) {
            int idx = tid + 256 * r;
            int row = idx >> 3, c4 = (idx & 7) * 4;
            *(float4*)&As[row][c4] = *(const float4*)(emb + (size_t)(tok0 + row) * ND + k0 + c4);
        }
        {
            int row = tid >> 3, c4 = (tid & 7) * 4;
            *(float4*)&Bs[row][c4] = *(const float4*)(Wsk + (size_t)(k0 + row) * NVAR + c4);
        }
        __syncthreads();
#pragma unroll
        for (int kk = 0; kk < 32; ++kk) {
            float4 bv = *(const float4*)&Bs[kk][cg * 4];
#pragma unroll
            for (int i = 0; i < 2; ++i) {
                float a = As[tg * 2 + i][kk];
                acc[i][0] += a * bv.x; acc[i][1] += a * bv.y;
                acc[i][2] += a * bv.z; acc[i][3] += a * bv.w;
            }
        }
        __syncthreads();
    }
    float4 bb = *(const float4*)(bsk + cg * 4);
#pragma unroll
    for (int i = 0; i < 2; ++i) {
        int tok = tok0 + tg * 2 + i;
        float4 o;
        o.x = acc[i][0] + bb.x; o.y = acc[i][1] + bb.y;
        o.z = acc[i][2] + bb.z; o.w = acc[i][3] + bb.w;
        *(float4*)(skip + (size_t)tok * NVAR + cg * 4) = o;
    }
}

// ---------------- selection: h2,g,glu,LN,softmax -> weights [8192,32] ----------------
__global__ __launch_bounds__(128) void k_sel(const float* __restrict__ h1,
        const float* __restrict__ skip,
        const float* __restrict__ W2, const float* __restrict__ b2,
        const float* __restrict__ Wg, const float* __restrict__ bg,
        const float* __restrict__ fg, const float* __restrict__ fb,
        float* __restrict__ wout) {
    int tok = blockIdx.x, t = threadIdx.x;
    __shared__ float hb[HDIM], h2b[HDIM], gb[64];
    hb[t] = h1[(size_t)tok * HDIM + t];
    __syncthreads();
    float acc = b2[t];
#pragma unroll 8
    for (int k = 0; k < HDIM; ++k) acc += hb[k] * W2[k * HDIM + t];
    h2b[t] = acc;
    __syncthreads();
    if (t < 64) {
        float g = bg[t];
#pragma unroll 8
        for (int k = 0; k < HDIM; ++k) g += h2b[k] * Wg[k * 64 + t];
        gb[t] = g;
    }
    __syncthreads();
    if (t < 32) {
        float a = gb[t], b = gb[t + 32];
        float val = a * sigm_f(b) + skip[(size_t)tok * NVAR + t];
        float s = val, q = val * val;
#pragma unroll
        for (int m = 16; m >= 1; m >>= 1) { s += __shfl_xor(s, m, 32); q += __shfl_xor(q, m, 32); }
        float mean = s * (1.f / 32.f);
        float var = q * (1.f / 32.f) - mean * mean;
        float logit = (val - mean) * rsqrtf(var + LN_EPS) * fg[t] + fb[t];
        float mx = logit;
#pragma unroll
        for (int m = 16; m >= 1; m >>= 1) mx = fmaxf(mx, __shfl_xor(mx, m, 32));
        float e = __expf(logit - mx);
        float se = e;
#pragma unroll
        for (int m = 16; m >= 1; m >>= 1) se += __shfl_xor(se, m, 32);
        wout[(size_t)tok * NVAR + t] = e / se;
    }
}

// ---------------- per-variable GRNs via MFMA + weighted accumulate ----------------
// grid (128 token-tiles, 32 n), block 256 (4 waves), TT=64.
// LDS pool 61440 B (ushort units):
//   VSB  [64][136] @ 0       (ph1 -> combine)
//   VH2B [64][136] @ 8704    (ph2 -> ph3)
//   EB   [64][72]  @ 17408   (stage -> ph1)
//   VHB  [64][136] @ 22016   (ph1 -> ph2)
//   VG   [64][264] @ 8704    (ph3 epilogue -> combine; overlays dead VH2B/EB/VHB)
__global__ __launch_bounds__(256, 2) void k_var(
        const float* __restrict__ emb,
        const unsigned short* __restrict__ pk1, const unsigned short* __restrict__ pksk,
        const unsigned short* __restrict__ pk2, const unsigned short* __restrict__ pkg,
        const float* __restrict__ vb1, const float* __restrict__ vbsk,
        const float* __restrict__ vb2, const float* __restrict__ vbg,
        const float* __restrict__ gam, const float* __restrict__ bet,
        const float* __restrict__ wsel, float* __restrict__ outp) {
    __shared__ __align__(16) unsigned short pool[30720];
    unsigned short* VSB  = pool;
    unsigned short* VH2B = pool + 8704;
    unsigned short* EB   = pool + 17408;
    unsigned short* VHB  = pool + 22016;
    unsigned short* VG   = pool + 8704;

    const int tid = threadIdx.x;
    const int lane = tid & 63;
    const int w = tid >> 6;
    const int lr = lane & 15;   // row (A) / col (B,D) within frag
    const int lk = lane >> 4;   // k-group
    const int tok0 = blockIdx.x * TT;
    const int n = blockIdx.y;

    // ---- stage E tile [64 tok][64] fp32 -> bf16 LDS (rows padded to 72) ----
    {
        int row = tid >> 2, c0 = (tid & 3) * 16;
        const float* src = emb + ((size_t)(tok0 + row) * NVAR + n) * DDIM + c0;
        unsigned short* dst = EB + row * 72 + c0;
#pragma unroll
        for (int q = 0; q < 4; ++q) {
            float4 v = *(const float4*)(src + q * 4);
            dst[q * 4 + 0] = f2bf(v.x); dst[q * 4 + 1] = f2bf(v.y);
            dst[q * 4 + 2] = f2bf(v.z); dst[q * 4 + 3] = f2bf(v.w);
        }
    }
    __syncthreads();

    // ---- phase 1: VH = elu(E@W1+b1), VS = E@Wsk+bsk.  M=64,N=128,K=64 ----
    {
        f32x4 c1[4][2] = {};
        f32x4 c2[4][2] = {};
#pragma unroll
        for (int ks = 0; ks < 2; ++ks) {
            s16x8 af[4];
#pragma unroll
            for (int mf = 0; mf < 4; ++mf)
                af[mf] = frag_ld(EB + (mf * 16 + lr) * 72 + ks * 32 + lk * 8);
            const unsigned short* p1 = pk1 + (size_t)n * 8192 + ((size_t)(ks * 8 + w * 2) * 64 + lane) * 8;
            const unsigned short* ps = pksk + (size_t)n * 8192 + ((size_t)(ks * 8 + w * 2) * 64 + lane) * 8;
            s16x8 b10 = frag_ld(p1), b11 = frag_ld(p1 + 512);
            s16x8 bs0 = frag_ld(ps), bs1 = frag_ld(ps + 512);
#pragma unroll
            for (int mf = 0; mf < 4; ++mf) {
                c1[mf][0] = mfma_bf16(af[mf], b10, c1[mf][0]);
                c1[mf][1] = mfma_bf16(af[mf], b11, c1[mf][1]);
                c2[mf][0] = mfma_bf16(af[mf], bs0, c2[mf][0]);
                c2[mf][1] = mfma_bf16(af[mf], bs1, c2[mf][1]);
            }
        }
#pragma unroll
        for (int nf = 0; nf < 2; ++nf) {
            int col = w * 32 + nf * 16 + lr;
            float bb1 = vb1[n * HDIM + col];
            float bbs = vbsk[n * HDIM + col];
#pragma unroll
            for (int mf = 0; mf < 4; ++mf)
#pragma unroll
                for (int r = 0; r < 4; ++r) {
                    int row = mf * 16 + lk * 4 + r;
                    VHB[row * 136 + col] = f2bf(elu_f(c1[mf][nf][r] + bb1));
                    VSB[row * 136 + col] = f2bf(c2[mf][nf][r] + bbs);
                }
        }
    }
    __syncthreads();

    // ---- phase 2: VH2 = VH@W2+b2.  M=64,N=128,K=128 ----
    {
        f32x4 c3[4][2] = {};
#pragma unroll
        for (int ks = 0; ks < 4; ++ks) {
            s16x8 af[4];
#pragma unroll
            for (int mf = 0; mf < 4; ++mf)
                af[mf] = frag_ld(VHB + (mf * 16 + lr) * 136 + ks * 32 + lk * 8);
            const unsigned short* p2 = pk2 + (size_t)n * 16384 + ((size_t)(ks * 8 + w * 2) * 64 + lane) * 8;
            s16x8 b0 = frag_ld(p2), b1 = frag_ld(p2 + 512);
#pragma unroll
            for (int mf = 0; mf < 4; ++mf) {
                c3[mf][0] = mfma_bf16(af[mf], b0, c3[mf][0]);
                c3[mf][1] = mfma_bf16(af[mf], b1, c3[mf][1]);
            }
        }
#pragma unroll
        for (int nf = 0; nf < 2; ++nf) {
            int col = w * 32 + nf * 16 + lr;
            float bb = vb2[n * HDIM + col];
#pragma unroll
            for (int mf = 0; mf < 4; ++mf)
#pragma unroll
                for (int r = 0; r < 4; ++r)
                    VH2B[(mf * 16 + lk * 4 + r) * 136 + col] = f2bf(c3[mf][nf][r] + bb);
        }
    }
    __syncthreads();

    // ---- phase 3: VG = VH2@Wg+bg.  M=64,N=256,K=128 ----
    {
        f32x4 c4[4][4] = {};
#pragma unroll
        for (int ks = 0; ks < 4; ++ks) {
            s16x8 af[4];
#pragma unroll
            for (int mf = 0; mf < 4; ++mf)
                af[mf] = frag_ld(VH2B + (mf * 16 + lr) * 136 + ks * 32 + lk * 8);
            const unsigned short* pg = pkg + (size_t)n * 32768 + ((size_t)(ks * 16 + w * 4) * 64 + lane) * 8;
#pragma unroll
            for (int nf = 0; nf < 4; ++nf) {
                s16x8 bg = frag_ld(pg + nf * 512);
#pragma unroll
                for (int mf = 0; mf < 4; ++mf)
                    c4[mf][nf] = mfma_bf16(af[mf], bg, c4[mf][nf]);
            }
        }
        __syncthreads();   // all reads of VH2B done before VG overlays it
#pragma unroll
        for (int nf = 0; nf < 4; ++nf) {
            int col = w * 64 + nf * 16 + lr;
            float bb = vbg[n * 256 + col];
#pragma unroll
            for (int mf = 0; mf < 4; ++mf)
#pragma unroll
                for (int r = 0; r < 4; ++r)
                    VG[(mf * 16 + lk * 4 + r) * 264 + col] = f2bf(c4[mf][nf][r] + bb);
        }
    }
    __syncthreads();

    // ---- combine: glu + vskip, LN, *gamma+beta, *weight, atomic accumulate ----
    {
        int c0 = lane * 2;
        float g0 = gam[n * HDIM + c0], g1 = gam[n * HDIM + c0 + 1];
        float be0 = bet[n * HDIM + c0], be1 = bet[n * HDIM + c0 + 1];
#pragma unroll 2
        for (int i = 0; i < 16; ++i) {
            int tr = w * 16 + i;
            float a0 = bf2f(VG[tr * 264 + c0]);
            float a1v = bf2f(VG[tr * 264 + c0 + 1]);
            float b0 = bf2f(VG[tr * 264 + 128 + c0]);
            float b1v = bf2f(VG[tr * 264 + 128 + c0 + 1]);
            float s0 = bf2f(VSB[tr * 136 + c0]);
            float s1 = bf2f(VSB[tr * 136 + c0 + 1]);
            float v0 = a0 * sigm_f(b0) + s0;
            float v1 = a1v * sigm_f(b1v) + s1;
            float s = v0 + v1, q = v0 * v0 + v1 * v1;
#pragma unroll
            for (int m = 32; m >= 1; m >>= 1) { s += __shfl_xor(s, m); q += __shfl_xor(q, m); }
            float mean = s * (1.f / 128.f);
            float var = q * (1.f / 128.f) - mean * mean;
            float inv = rsqrtf(var + LN_EPS);
            float t0 = (v0 - mean) * inv * g0 + be0;
            float t1 = (v1 - mean) * inv * g1 + be1;
            float wgt = wsel[(size_t)(tok0 + tr) * NVAR + n];
            float* po = outp + (size_t)(tok0 + tr) * HDIM + c0;
            atomicAdd(po, wgt * t0);
            atomicAdd(po + 1, wgt * t1);
        }
    }
}

extern "C" void kernel_launch(void* const* d_in, const int* in_sizes, int n_in,
                              void* d_out, int out_size, void* d_ws, size_t ws_size,
                              hipStream_t stream) {
    const float* emb  = (const float*)d_in[0];
    const float* ctx  = (const float*)d_in[1];
    const float* fWsk = (const float*)d_in[2];
    const float* fbsk = (const float*)d_in[3];
    const float* fW1  = (const float*)d_in[4];
    const float* fb1  = (const float*)d_in[5];
    const float* fWc  = (const float*)d_in[6];
    const float* fW2  = (const float*)d_in[7];
    const float* fb2  = (const float*)d_in[8];
    const float* fWg  = (const float*)d_in[9];
    const float* fbg  = (const float*)d_in[10];
    const float* fg   = (const float*)d_in[11];
    const float* fb   = (const float*)d_in[12];
    const float* vWsk = (const float*)d_in[13];
    const float* vbsk = (const float*)d_in[14];
    const float* vW1  = (const float*)d_in[15];
    const float* vb1  = (const float*)d_in[16];
    const float* vW2  = (const float*)d_in[17];
    const float* vb2  = (const float*)d_in[18];
    const float* vWg  = (const float*)d_in[19];
    const float* vbg  = (const float*)d_in[20];
    const float* vgam = (const float*)d_in[21];
    const float* vbet = (const float*)d_in[22];

    float* outp = (float*)d_out;                       // [8192][128]
    float* wout = outp + (size_t)TOK * HDIM;           // [8192][32]
    float* ctxp = (float*)d_ws;                        // [64][128]
    float* h1   = ctxp + 64 * HDIM;                    // [8192][128]
    float* skip = h1 + (size_t)TOK * HDIM;             // [8192][32]
    unsigned short* pk1  = (unsigned short*)(skip + (size_t)TOK * NVAR);  // [32][64][128] frag-packed
    unsigned short* pksk = pk1 + 262144;
    unsigned short* pk2  = pksk + 262144;              // [32][128][128]
    unsigned short* pkg  = pk2 + 524288;               // [32][128][256]

    hipMemsetAsync(d_out, 0, (size_t)TOK * HDIM * sizeof(float), stream);
    k_pack<<<dim3(16, 32), 64, 0, stream>>>(vW1, pk1, DDIM, HDIM);
    k_pack<<<dim3(16, 32), 64, 0, stream>>>(vWsk, pksk, DDIM, HDIM);
    k_pack<<<dim3(32, 32), 64, 0, stream>>>(vW2, pk2, HDIM, HDIM);
    k_pack<<<dim3(64, 32), 64, 0, stream>>>(vWg, pkg, HDIM, 2 * HDIM);
    k_ctx<<<64, 128, 0, stream>>>(ctx, fWc, ctxp);
    k_h1<<<256, 256, 0, stream>>>(emb, fW1, fb1, ctxp, h1);
    k_skip<<<128, 256, 0, stream>>>(emb, fWsk, fbsk, skip);
    k_sel<<<TOK, 128, 0, stream>>>(h1, skip, fW2, fb2, fWg, fbg, fg, fb, wout);
    k_var<<<dim3(TOK / TT, NVAR), 256, 0, stream>>>(emb, pk1, pksk, pk2, pkg,
                                                    vb1, vbsk, vb2, vbg, vgam, vbet,
                                                    wout, outp);
}

// Round 4
// 358.272 us; speedup vs baseline: 2.2431x; 1.2935x over previous
//
#include <hip/hip_runtime.h>
#include <hip/hip_bf16.h>

#define TOK   8192      // B*T
#define NVAR  32
#define DDIM  64
#define HDIM  128
#define CDIM  64
#define ND    2048      // N*D
#define LN_EPS 1e-5f
#define TT 64

typedef float f32x4 __attribute__((ext_vector_type(4)));
typedef short s16x8 __attribute__((ext_vector_type(8)));
typedef unsigned short u16x8 __attribute__((ext_vector_type(8)));

__device__ __forceinline__ float bf2f(unsigned short u) {
    unsigned int x = ((unsigned int)u) << 16;
    return __uint_as_float(x);
}
__device__ __forceinline__ unsigned short f2bf(float f) {
    unsigned int x = __float_as_uint(f);
    unsigned int r = (x + 0x7fffu + ((x >> 16) & 1u)) >> 16;
    return (unsigned short)r;
}
__device__ __forceinline__ float elu_f(float x) {
    return x > 0.f ? x : (__expf(x) - 1.f);
}
__device__ __forceinline__ float sigm_f(float x) {
    return 1.f / (1.f + __expf(-x));
}
__device__ __forceinline__ s16x8 frag_ld(const unsigned short* p) {
    return __builtin_bit_cast(s16x8, *(const u16x8*)p);
}
__device__ __forceinline__ f32x4 mfma_bf16(s16x8 a, s16x8 b, f32x4 c) {
    return __builtin_amdgcn_mfma_f32_16x16x32_bf16(a, b, c, 0, 0, 0);
}

// ---------------- pack weight W[n][K][N] fp32 -> fragment-major bf16 ----------------
// out[n][ks][nf][lane][8]: element = W[n][ks*32 + (lane>>4)*8 + j][nf*16 + (lane&15)]
__global__ void k_pack(const float* __restrict__ W, unsigned short* __restrict__ out,
                       int K, int N) {
    int NF = N >> 4;
    int bx = blockIdx.x;              // ks*NF + nf
    int ks = bx / NF, nf = bx - ks * NF;
    int n = blockIdx.y;
    int lane = threadIdx.x;
    int col = nf * 16 + (lane & 15);
    int k0 = ks * 32 + (lane >> 4) * 8;
    const float* src = W + (size_t)n * K * N + (size_t)k0 * N + col;
    unsigned short* dst = out + (size_t)n * K * N + ((size_t)bx * 64 + lane) * 8;
    unsigned short v[8];
#pragma unroll
    for (int j = 0; j < 8; ++j) v[j] = f2bf(src[(size_t)j * N]);
    *(u16x8*)dst = *(const u16x8*)v;
}

// ---------------- ctx_proj = context @ f_Wc  [64,128] ----------------
__global__ void k_ctx(const float* __restrict__ ctx, const float* __restrict__ Wc,
                      float* __restrict__ ctxp) {
    int b = blockIdx.x, h = threadIdx.x;
    __shared__ float cs[CDIM];
    if (threadIdx.x < CDIM) cs[threadIdx.x] = ctx[b * CDIM + threadIdx.x];
    __syncthreads();
    float acc = 0.f;
#pragma unroll
    for (int c = 0; c < CDIM; ++c) acc += cs[c] * Wc[c * HDIM + h];
    ctxp[b * HDIM + h] = acc;
}

// ---------------- h1 = elu(flat @ f_W1 + b1 + ctxp)  [8192,128] ----------------
__global__ __launch_bounds__(256) void k_h1(const float* __restrict__ emb,
        const float* __restrict__ W1, const float* __restrict__ b1,
        const float* __restrict__ ctxp, float* __restrict__ h1) {
    __shared__ float As[32][36];
    __shared__ float Bs[32][128];
    int tid = threadIdx.x;
    int tok0 = blockIdx.x * 32;
    int cg = tid & 31, tg = tid >> 5;
    float acc[4][4] = {};
    for (int k0 = 0; k0 < ND; k0 += 32) {
        {
            int row = tid >> 3, c4 = (tid & 7) * 4;
            *(float4*)&As[row][c4] = *(const float4*)(emb + (size_t)(tok0 + row) * ND + k0 + c4);
        }
#pragma unroll
        for (int r = 0; r < 4; ++r) {
            int idx = tid + 256 * r;
            int row = idx >> 5, c4 = (idx & 31) * 4;
            *(float4*)&Bs[row][c4] = *(const float4*)(W1 + (size_t)(k0 + row) * HDIM + c4);
        }
        __syncthreads();
#pragma unroll
        for (int kk = 0; kk < 32; ++kk) {
            float4 bv = *(const float4*)&Bs[kk][cg * 4];
#pragma unroll
            for (int i = 0; i < 4; ++i) {
                float a = As[tg * 4 + i][kk];
                acc[i][0] += a * bv.x; acc[i][1] += a * bv.y;
                acc[i][2] += a * bv.z; acc[i][3] += a * bv.w;
            }
        }
        __syncthreads();
    }
    float4 bb = *(const float4*)(b1 + cg * 4);
#pragma unroll
    for (int i = 0; i < 4; ++i) {
        int tok = tok0 + tg * 4 + i;
        int b = tok >> 7;
        float4 cc = *(const float4*)(ctxp + b * HDIM + cg * 4);
        float4 o;
        o.x = elu_f(acc[i][0] + bb.x + cc.x);
        o.y = elu_f(acc[i][1] + bb.y + cc.y);
        o.z = elu_f(acc[i][2] + bb.z + cc.z);
        o.w = elu_f(acc[i][3] + bb.w + cc.w);
        *(float4*)(h1 + (size_t)tok * HDIM + cg * 4) = o;
    }
}

// ---------------- skip = flat @ f_Wskip + bskip  [8192,32] ----------------
__global__ __launch_bounds__(256) void k_skip(const float* __restrict__ emb,
        const float* __restrict__ Wsk, const float* __restrict__ bsk,
        float* __restrict__ skip) {
    __shared__ float As[64][36];
    __shared__ float Bs[32][36];
    int tid = threadIdx.x;
    int tok0 = blockIdx.x * 64;
    int cg = tid & 7, tg = tid >> 3;
    float acc[2][4] = {};
    for (int k0 = 0; k0 < ND; k0 += 32) {
#pragma unroll
        for (int r = 0; r < 2; ++r) {
            int idx = tid + 256 * r;
            int row = idx >> 3, c4 = (idx & 7) * 4;
            *(float4*)&As[row][c4] = *(const float4*)(emb + (size_t)(tok0 + row) * ND + k0 + c4);
        }
        {
            int row = tid >> 3, c4 = (tid & 7) * 4;
            *(float4*)&Bs[row][c4] = *(const float4*)(Wsk + (size_t)(k0 + row) * NVAR + c4);
        }
        __syncthreads();
#pragma unroll
        for (int kk = 0; kk < 32; ++kk) {
            float4 bv = *(const float4*)&Bs[kk][cg * 4];
#pragma unroll
            for (int i = 0; i < 2; ++i) {
                float a = As[tg * 2 + i][kk];
                acc[i][0] += a * bv.x; acc[i][1] += a * bv.y;
                acc[i][2] += a * bv.z; acc[i][3] += a * bv.w;
            }
        }
        __syncthreads();
    }
    float4 bb = *(const float4*)(bsk + cg * 4);
#pragma unroll
    for (int i = 0; i < 2; ++i) {
        int tok = tok0 + tg * 2 + i;
        float4 o;
        o.x = acc[i][0] + bb.x; o.y = acc[i][1] + bb.y;
        o.z = acc[i][2] + bb.z; o.w = acc[i][3] + bb.w;
        *(float4*)(skip + (size_t)tok * NVAR + cg * 4) = o;
    }
}

// ---------------- selection: h2,g,glu,LN,softmax -> weights [8192,32] ----------------
__global__ __launch_bounds__(128) void k_sel(const float* __restrict__ h1,
        const float* __restrict__ skip,
        const float* __restrict__ W2, const float* __restrict__ b2,
        const float* __restrict__ Wg, const float* __restrict__ bg,
        const float* __restrict__ fg, const float* __restrict__ fb,
        float* __restrict__ wout) {
    int tok = blockIdx.x, t = threadIdx.x;
    __shared__ float hb[HDIM], h2b[HDIM], gb[64];
    hb[t] = h1[(size_t)tok * HDIM + t];
    __syncthreads();
    float acc = b2[t];
#pragma unroll 8
    for (int k = 0; k < HDIM; ++k) acc += hb[k] * W2[k * HDIM + t];
    h2b[t] = acc;
    __syncthreads();
    if (t < 64) {
        float g = bg[t];
#pragma unroll 8
        for (int k = 0; k < HDIM; ++k) g += h2b[k] * Wg[k * 64 + t];
        gb[t] = g;
    }
    __syncthreads();
    if (t < 32) {
        float a = gb[t], b = gb[t + 32];
        float val = a * sigm_f(b) + skip[(size_t)tok * NVAR + t];
        float s = val, q = val * val;
#pragma unroll
        for (int m = 16; m >= 1; m >>= 1) { s += __shfl_xor(s, m, 32); q += __shfl_xor(q, m, 32); }
        float mean = s * (1.f / 32.f);
        float var = q * (1.f / 32.f) - mean * mean;
        float logit = (val - mean) * rsqrtf(var + LN_EPS) * fg[t] + fb[t];
        float mx = logit;
#pragma unroll
        for (int m = 16; m >= 1; m >>= 1) mx = fmaxf(mx, __shfl_xor(mx, m, 32));
        float e = __expf(logit - mx);
        float se = e;
#pragma unroll
        for (int m = 16; m >= 1; m >>= 1) se += __shfl_xor(se, m, 32);
        wout[(size_t)tok * NVAR + t] = e / se;
    }
}

// ---------------- per-variable GRNs via MFMA, 8 n per block, reg-accumulated ----------------
// grid (128 token-tiles, 4 n-groups), block 256 (4 waves), TT=64.
// LDS pool 61440 B (ushort units) — VG does NOT overlay EB:
//   VSB  [64][136] @ 0       EB  [64][72]  @ 8704
//   VH2B [64][136] @ 13312   VHB [64][136] @ 22016
//   VG   [64][264] @ 13312   (overlays dead VH2B+VHB only)
__global__ __launch_bounds__(256, 2) void k_var(
        const float* __restrict__ emb,
        const unsigned short* __restrict__ pk1, const unsigned short* __restrict__ pksk,
        const unsigned short* __restrict__ pk2, const unsigned short* __restrict__ pkg,
        const float* __restrict__ vb1, const float* __restrict__ vbsk,
        const float* __restrict__ vb2, const float* __restrict__ vbg,
        const float* __restrict__ gam, const float* __restrict__ bet,
        const float* __restrict__ wsel, float* __restrict__ outp) {
    __shared__ __align__(16) unsigned short pool[30720];
    unsigned short* VSB  = pool;
    unsigned short* EB   = pool + 8704;
    unsigned short* VH2B = pool + 13312;
    unsigned short* VHB  = pool + 22016;
    unsigned short* VG   = pool + 13312;

    const int tid = threadIdx.x;
    const int lane = tid & 63;
    const int w = tid >> 6;
    const int lr = lane & 15;
    const int lk = lane >> 4;
    const int tok0 = blockIdx.x * TT;
    const int gbase = blockIdx.y * 8;

    float accO[16][2];
#pragma unroll
    for (int i = 0; i < 16; ++i) { accO[i][0] = 0.f; accO[i][1] = 0.f; }

    for (int nn = 0; nn < 8; ++nn) {
        const int n = gbase + nn;

        // ---- stage E tile [64 tok][64] fp32 -> bf16 LDS ----
        {
            int row = tid >> 2, c0 = (tid & 3) * 16;
            const float* src = emb + ((size_t)(tok0 + row) * NVAR + n) * DDIM + c0;
            unsigned short* dst = EB + row * 72 + c0;
#pragma unroll
            for (int q = 0; q < 4; ++q) {
                float4 v = *(const float4*)(src + q * 4);
                dst[q * 4 + 0] = f2bf(v.x); dst[q * 4 + 1] = f2bf(v.y);
                dst[q * 4 + 2] = f2bf(v.z); dst[q * 4 + 3] = f2bf(v.w);
            }
        }
        __syncthreads();

        // ---- phase 1: VH = elu(E@W1+b1), VS = E@Wsk+bsk ----
        {
            f32x4 c1[4][2] = {};
            f32x4 c2[4][2] = {};
#pragma unroll
            for (int ks = 0; ks < 2; ++ks) {
                s16x8 af[4];
#pragma unroll
                for (int mf = 0; mf < 4; ++mf)
                    af[mf] = frag_ld(EB + (mf * 16 + lr) * 72 + ks * 32 + lk * 8);
                const unsigned short* p1 = pk1 + (size_t)n * 8192 + ((size_t)(ks * 8 + w * 2) * 64 + lane) * 8;
                const unsigned short* ps = pksk + (size_t)n * 8192 + ((size_t)(ks * 8 + w * 2) * 64 + lane) * 8;
                s16x8 b10 = frag_ld(p1), b11 = frag_ld(p1 + 512);
                s16x8 bs0 = frag_ld(ps), bs1 = frag_ld(ps + 512);
#pragma unroll
                for (int mf = 0; mf < 4; ++mf) {
                    c1[mf][0] = mfma_bf16(af[mf], b10, c1[mf][0]);
                    c1[mf][1] = mfma_bf16(af[mf], b11, c1[mf][1]);
                    c2[mf][0] = mfma_bf16(af[mf], bs0, c2[mf][0]);
                    c2[mf][1] = mfma_bf16(af[mf], bs1, c2[mf][1]);
                }
            }
#pragma unroll
            for (int nf = 0; nf < 2; ++nf) {
                int col = w * 32 + nf * 16 + lr;
                float bb1 = vb1[n * HDIM + col];
                float bbs = vbsk[n * HDIM + col];
#pragma unroll
                for (int mf = 0; mf < 4; ++mf)
#pragma unroll
                    for (int r = 0; r < 4; ++r) {
                        int row = mf * 16 + lk * 4 + r;
                        VHB[row * 136 + col] = f2bf(elu_f(c1[mf][nf][r] + bb1));
                        VSB[row * 136 + col] = f2bf(c2[mf][nf][r] + bbs);
                    }
            }
        }
        __syncthreads();

        // ---- phase 2: VH2 = VH@W2+b2 ----
        {
            f32x4 c3[4][2] = {};
#pragma unroll
            for (int ks = 0; ks < 4; ++ks) {
                s16x8 af[4];
#pragma unroll
                for (int mf = 0; mf < 4; ++mf)
                    af[mf] = frag_ld(VHB + (mf * 16 + lr) * 136 + ks * 32 + lk * 8);
                const unsigned short* p2 = pk2 + (size_t)n * 16384 + ((size_t)(ks * 8 + w * 2) * 64 + lane) * 8;
                s16x8 b0 = frag_ld(p2), b1 = frag_ld(p2 + 512);
#pragma unroll
                for (int mf = 0; mf < 4; ++mf) {
                    c3[mf][0] = mfma_bf16(af[mf], b0, c3[mf][0]);
                    c3[mf][1] = mfma_bf16(af[mf], b1, c3[mf][1]);
                }
            }
#pragma unroll
            for (int nf = 0; nf < 2; ++nf) {
                int col = w * 32 + nf * 16 + lr;
                float bb = vb2[n * HDIM + col];
#pragma unroll
                for (int mf = 0; mf < 4; ++mf)
#pragma unroll
                    for (int r = 0; r < 4; ++r)
                        VH2B[(mf * 16 + lk * 4 + r) * 136 + col] = f2bf(c3[mf][nf][r] + bb);
            }
        }
        __syncthreads();

        // ---- phase 3: VG = VH2@Wg+bg ----
        {
            f32x4 c4[4][4] = {};
#pragma unroll
            for (int ks = 0; ks < 4; ++ks) {
                s16x8 af[4];
#pragma unroll
                for (int mf = 0; mf < 4; ++mf)
                    af[mf] = frag_ld(VH2B + (mf * 16 + lr) * 136 + ks * 32 + lk * 8);
                const unsigned short* pg = pkg + (size_t)n * 32768 + ((size_t)(ks * 16 + w * 4) * 64 + lane) * 8;
#pragma unroll
                for (int nf = 0; nf < 4; ++nf) {
                    s16x8 bg = frag_ld(pg + nf * 512);
#pragma unroll
                    for (int mf = 0; mf < 4; ++mf)
                        c4[mf][nf] = mfma_bf16(af[mf], bg, c4[mf][nf]);
                }
            }
            __syncthreads();   // all VH2B reads done before VG overlays VH2B/VHB
#pragma unroll
            for (int nf = 0; nf < 4; ++nf) {
                int col = w * 64 + nf * 16 + lr;
                float bb = vbg[n * 256 + col];
#pragma unroll
                for (int mf = 0; mf < 4; ++mf)
#pragma unroll
                    for (int r = 0; r < 4; ++r)
                        VG[(mf * 16 + lk * 4 + r) * 264 + col] = f2bf(c4[mf][nf][r] + bb);
            }
        }
        __syncthreads();

        // ---- combine: glu + vskip, LN, *gamma+beta, *weight, accumulate in regs ----
        {
            int c0 = lane * 2;
            float g0 = gam[n * HDIM + c0], g1 = gam[n * HDIM + c0 + 1];
            float be0 = bet[n * HDIM + c0], be1 = bet[n * HDIM + c0 + 1];
#pragma unroll 2
            for (int i = 0; i < 16; ++i) {
                int tr = w * 16 + i;
                float a0 = bf2f(VG[tr * 264 + c0]);
                float a1v = bf2f(VG[tr * 264 + c0 + 1]);
                float b0 = bf2f(VG[tr * 264 + 128 + c0]);
                float b1v = bf2f(VG[tr * 264 + 128 + c0 + 1]);
                float s0 = bf2f(VSB[tr * 136 + c0]);
                float s1 = bf2f(VSB[tr * 136 + c0 + 1]);
                float v0 = a0 * sigm_f(b0) + s0;
                float v1 = a1v * sigm_f(b1v) + s1;
                float s = v0 + v1, q = v0 * v0 + v1 * v1;
#pragma unroll
                for (int m = 32; m >= 1; m >>= 1) { s += __shfl_xor(s, m); q += __shfl_xor(q, m); }
                float mean = s * (1.f / 128.f);
                float var = q * (1.f / 128.f) - mean * mean;
                float inv = rsqrtf(var + LN_EPS);
                float t0 = (v0 - mean) * inv * g0 + be0;
                float t1 = (v1 - mean) * inv * g1 + be1;
                float wgt = wsel[(size_t)(tok0 + tr) * NVAR + n];
                accO[i][0] += wgt * t0;
                accO[i][1] += wgt * t1;
            }
        }
        __syncthreads();   // combine reads done before next iteration's writes
    }

    // ---- one atomic per element per n-group ----
    {
        int c0 = lane * 2;
#pragma unroll
        for (int i = 0; i < 16; ++i) {
            float* po = outp + (size_t)(tok0 + w * 16 + i) * HDIM + c0;
            atomicAdd(po, accO[i][0]);
            atomicAdd(po + 1, accO[i][1]);
        }
    }
}

extern "C" void kernel_launch(void* const* d_in, const int* in_sizes, int n_in,
                              void* d_out, int out_size, void* d_ws, size_t ws_size,
                              hipStream_t stream) {
    const float* emb  = (const float*)d_in[0];
    const float* ctx  = (const float*)d_in[1];
    const float* fWsk = (const float*)d_in[2];
    const float* fbsk = (const float*)d_in[3];
    const float* fW1  = (const float*)d_in[4];
    const float* fb1  = (const float*)d_in[5];
    const float* fWc  = (const float*)d_in[6];
    const float* fW2  = (const float*)d_in[7];
    const float* fb2  = (const float*)d_in[8];
    const float* fWg  = (const float*)d_in[9];
    const float* fbg  = (const float*)d_in[10];
    const float* fg   = (const float*)d_in[11];
    const float* fb   = (const float*)d_in[12];
    const float* vWsk = (const float*)d_in[13];
    const float* vbsk = (const float*)d_in[14];
    const float* vW1  = (const float*)d_in[15];
    const float* vb1  = (const float*)d_in[16];
    const float* vW2  = (const float*)d_in[17];
    const float* vb2  = (const float*)d_in[18];
    const float* vWg  = (const float*)d_in[19];
    const float* vbg  = (const float*)d_in[20];
    const float* vgam = (const float*)d_in[21];
    const float* vbet = (const float*)d_in[22];

    float* outp = (float*)d_out;                       // [8192][128]
    float* wout = outp + (size_t)TOK * HDIM;           // [8192][32]
    float* ctxp = (float*)d_ws;                        // [64][128]
    float* h1   = ctxp + 64 * HDIM;                    // [8192][128]
    float* skip = h1 + (size_t)TOK * HDIM;             // [8192][32]
    unsigned short* pk1  = (unsigned short*)(skip + (size_t)TOK * NVAR);  // [32][64][128]
    unsigned short* pksk = pk1 + 262144;
    unsigned short* pk2  = pksk + 262144;              // [32][128][128]
    unsigned short* pkg  = pk2 + 524288;               // [32][128][256]

    hipMemsetAsync(d_out, 0, (size_t)TOK * HDIM * sizeof(float), stream);
    k_pack<<<dim3(16, 32), 64, 0, stream>>>(vW1, pk1, DDIM, HDIM);
    k_pack<<<dim3(16, 32), 64, 0, stream>>>(vWsk, pksk, DDIM, HDIM);
    k_pack<<<dim3(32, 32), 64, 0, stream>>>(vW2, pk2, HDIM, HDIM);
    k_pack<<<dim3(64, 32), 64, 0, stream>>>(vWg, pkg, HDIM, 2 * HDIM);
    k_ctx<<<64, 128, 0, stream>>>(ctx, fWc, ctxp);
    k_h1<<<256, 256, 0, stream>>>(emb, fW1, fb1, ctxp, h1);
    k_skip<<<128, 256, 0, stream>>>(emb, fWsk, fbsk, skip);
    k_sel<<<TOK, 128, 0, stream>>>(h1, skip, fW2, fb2, fWg, fbg, fg, fb, wout);
    k_var<<<dim3(TOK / TT, 4), 256, 0, stream>>>(emb, pk1, pksk, pk2, pkg,
                                                 vb1, vbsk, vb2, vbg, vgam, vbet,
                                                 wout, outp);
}

// Round 5
// 223.952 us; speedup vs baseline: 3.5884x; 1.5998x over previous
//
#include <hip/hip_runtime.h>
#include <hip/hip_bf16.h>

#define TOK   8192      // B*T
#define NVAR  32
#define DDIM  64
#define HDIM  128
#define CDIM  64
#define ND    2048      // N*D
#define LN_EPS 1e-5f
#define TT 64

typedef float f32x4 __attribute__((ext_vector_type(4)));
typedef short s16x8 __attribute__((ext_vector_type(8)));
typedef unsigned short u16x8 __attribute__((ext_vector_type(8)));

__device__ __forceinline__ float bf2f(unsigned short u) {
    unsigned int x = ((unsigned int)u) << 16;
    return __uint_as_float(x);
}
__device__ __forceinline__ unsigned short f2bf(float f) {
    unsigned int x = __float_as_uint(f);
    unsigned int r = (x + 0x7fffu + ((x >> 16) & 1u)) >> 16;
    return (unsigned short)r;
}
__device__ __forceinline__ float elu_f(float x) {
    return x > 0.f ? x : (__expf(x) - 1.f);
}
__device__ __forceinline__ float sigm_f(float x) {
    return 1.f / (1.f + __expf(-x));
}
__device__ __forceinline__ s16x8 frag_ld(const unsigned short* p) {
    return __builtin_bit_cast(s16x8, *(const u16x8*)p);
}
__device__ __forceinline__ f32x4 mfma_bf16(s16x8 a, s16x8 b, f32x4 c) {
    return __builtin_amdgcn_mfma_f32_16x16x32_bf16(a, b, c, 0, 0, 0);
}

// ---------------- pack weight W[n][K][N] fp32 -> fragment-major bf16 ----------------
// out[n][ks][nf][lane][8]: element = W[n][ks*32 + (lane>>4)*8 + j][nf*16 + (lane&15)]
__global__ void k_pack(const float* __restrict__ W, unsigned short* __restrict__ out,
                       int K, int N) {
    int NF = N >> 4;
    int bx = blockIdx.x;              // ks*NF + nf
    int ks = bx / NF, nf = bx - ks * NF;
    int n = blockIdx.y;
    int lane = threadIdx.x;
    int col = nf * 16 + (lane & 15);
    int k0 = ks * 32 + (lane >> 4) * 8;
    const float* src = W + (size_t)n * K * N + (size_t)k0 * N + col;
    unsigned short* dst = out + (size_t)n * K * N + ((size_t)bx * 64 + lane) * 8;
    unsigned short v[8];
#pragma unroll
    for (int j = 0; j < 8; ++j) v[j] = f2bf(src[(size_t)j * N]);
    *(u16x8*)dst = *(const u16x8*)v;
}

// ---------------- ctx_proj = context @ f_Wc  [64,128] ----------------
__global__ void k_ctx(const float* __restrict__ ctx, const float* __restrict__ Wc,
                      float* __restrict__ ctxp) {
    int b = blockIdx.x, h = threadIdx.x;
    __shared__ float cs[CDIM];
    if (threadIdx.x < CDIM) cs[threadIdx.x] = ctx[b * CDIM + threadIdx.x];
    __syncthreads();
    float acc = 0.f;
#pragma unroll
    for (int c = 0; c < CDIM; ++c) acc += cs[c] * Wc[c * HDIM + h];
    ctxp[b * HDIM + h] = acc;
}

// ---------------- flatten GRN part 1 via MFMA: h1(bf16) + skip(f32) ----------------
// [8192,2048] @ [2048,160].  grid 256 x 32-token tiles, block 128 (2 waves, mf=w).
__global__ __launch_bounds__(128) void k_flat(const float* __restrict__ emb,
        const unsigned short* __restrict__ pfW1, const unsigned short* __restrict__ pfWsk,
        const float* __restrict__ fb1, const float* __restrict__ fbsk,
        const float* __restrict__ ctxp,
        unsigned short* __restrict__ h1b, float* __restrict__ skip) {
    const int tid = threadIdx.x;
    const int lane = tid & 63;
    const int w = tid >> 6;            // 0..1
    const int lr = lane & 15, lk = lane >> 4;
    const int tok0 = blockIdx.x * 32;
    const float* arow = emb + (size_t)(tok0 + w * 16 + lr) * ND + lk * 8;
    f32x4 acc[10] = {};
    for (int ks = 0; ks < 64; ++ks) {
        float4 a0 = *(const float4*)(arow + ks * 32);
        float4 a1 = *(const float4*)(arow + ks * 32 + 4);
        unsigned short av[8];
        av[0] = f2bf(a0.x); av[1] = f2bf(a0.y); av[2] = f2bf(a0.z); av[3] = f2bf(a0.w);
        av[4] = f2bf(a1.x); av[5] = f2bf(a1.y); av[6] = f2bf(a1.z); av[7] = f2bf(a1.w);
        s16x8 af = __builtin_bit_cast(s16x8, *(u16x8*)av);
#pragma unroll
        for (int nf = 0; nf < 8; ++nf) {
            s16x8 bf = frag_ld(pfW1 + ((size_t)(ks * 8 + nf) * 64 + lane) * 8);
            acc[nf] = mfma_bf16(af, bf, acc[nf]);
        }
#pragma unroll
        for (int nf = 0; nf < 2; ++nf) {
            s16x8 bf = frag_ld(pfWsk + ((size_t)(ks * 2 + nf) * 64 + lane) * 8);
            acc[8 + nf] = mfma_bf16(af, bf, acc[8 + nf]);
        }
    }
    const int b = tok0 >> 7;           // uniform per block (32 | 128)
#pragma unroll
    for (int nf = 0; nf < 8; ++nf) {
        int col = nf * 16 + lr;
        float add = fb1[col] + ctxp[b * HDIM + col];
#pragma unroll
        for (int r = 0; r < 4; ++r) {
            int tok = tok0 + w * 16 + lk * 4 + r;
            h1b[(size_t)tok * HDIM + col] = f2bf(elu_f(acc[nf][r] + add));
        }
    }
#pragma unroll
    for (int nf = 0; nf < 2; ++nf) {
        int col = nf * 16 + lr;
        float add = fbsk[col];
#pragma unroll
        for (int r = 0; r < 4; ++r) {
            int tok = tok0 + w * 16 + lk * 4 + r;
            skip[(size_t)tok * NVAR + col] = acc[8 + nf][r] + add;
        }
    }
}

// ---------------- selection via MFMA: h2, gates, glu+LN+softmax -> weights ----------------
// grid 256 x 32-token tiles, block 128 (2 waves).
// LDS: H1 [32][136]us @0, H2 [32][136]us @4352; G [32][68]f32 overlays H1
// (all H1 reads end at the phase-A barrier).
__global__ __launch_bounds__(128) void k_sel(const unsigned short* __restrict__ h1b,
        const float* __restrict__ skip,
        const unsigned short* __restrict__ pfW2, const float* __restrict__ fb2,
        const unsigned short* __restrict__ pfWg, const float* __restrict__ fbg,
        const float* __restrict__ fg, const float* __restrict__ fb,
        float* __restrict__ wout) {
    __shared__ __align__(16) unsigned short pool[8704];
    unsigned short* H1 = pool;            // [32][136]
    unsigned short* H2 = pool + 4352;     // [32][136]
    const int tid = threadIdx.x;
    const int lane = tid & 63, w = tid >> 6, lr = lane & 15, lk = lane >> 4;
    const int tok0 = blockIdx.x * 32;

    // stage h1 tile (already bf16)
    {
        int row = tid >> 2, seg = (tid & 3) * 32;
#pragma unroll
        for (int q = 0; q < 4; ++q)
            *(u16x8*)(H1 + row * 136 + seg + q * 8) =
                *(const u16x8*)(h1b + (size_t)(tok0 + row) * HDIM + seg + q * 8);
    }
    __syncthreads();

    // phase A: H2 = H1@W2 + b2   (M=32,N=128,K=128)
    {
        f32x4 acc[8] = {};
#pragma unroll
        for (int ks = 0; ks < 4; ++ks) {
            s16x8 af = frag_ld(H1 + (w * 16 + lr) * 136 + ks * 32 + lk * 8);
#pragma unroll
            for (int nf = 0; nf < 8; ++nf) {
                s16x8 bf = frag_ld(pfW2 + ((size_t)(ks * 8 + nf) * 64 + lane) * 8);
                acc[nf] = mfma_bf16(af, bf, acc[nf]);
            }
        }
#pragma unroll
        for (int nf = 0; nf < 8; ++nf) {
            int col = nf * 16 + lr;
            float add = fb2[col];
#pragma unroll
            for (int r = 0; r < 4; ++r)
                H2[(w * 16 + lk * 4 + r) * 136 + col] = f2bf(acc[nf][r] + add);
        }
    }
    __syncthreads();   // all H1 reads done; G may overlay H1 after this point

    // phase B: G = H2@Wg + bg   (M=32,N=64,K=128), fp32 into LDS
    float* G = (float*)pool;              // [32][68], overlays H1 only
    {
        f32x4 acc[4] = {};
#pragma unroll
        for (int ks = 0; ks < 4; ++ks) {
            s16x8 af = frag_ld(H2 + (w * 16 + lr) * 136 + ks * 32 + lk * 8);
#pragma unroll
            for (int nf = 0; nf < 4; ++nf) {
                s16x8 bf = frag_ld(pfWg + ((size_t)(ks * 4 + nf) * 64 + lane) * 8);
                acc[nf] = mfma_bf16(af, bf, acc[nf]);
            }
        }
#pragma unroll
        for (int nf = 0; nf < 4; ++nf) {
            int col = nf * 16 + lr;
            float add = fbg[col];
#pragma unroll
            for (int r = 0; r < 4; ++r)
                G[(w * 16 + lk * 4 + r) * 68 + col] = acc[nf][r] + add;
        }
    }
    __syncthreads();

    // phase C: glu + skip, LN(32), softmax(32) -> weights
    {
        int grp = tid >> 5, t = tid & 31;
        float fgv = fg[t], fbv = fb[t];
#pragma unroll 2
        for (int j = 0; j < 8; ++j) {
            int tr = grp * 8 + j;
            float a = G[tr * 68 + t];
            float bb = G[tr * 68 + 32 + t];
            float val = a * sigm_f(bb) + skip[(size_t)(tok0 + tr) * NVAR + t];
            float s = val, q = val * val;
#pragma unroll
            for (int m = 16; m >= 1; m >>= 1) { s += __shfl_xor(s, m, 32); q += __shfl_xor(q, m, 32); }
            float mean = s * (1.f / 32.f);
            float var = q * (1.f / 32.f) - mean * mean;
            float logit = (val - mean) * rsqrtf(var + LN_EPS) * fgv + fbv;
            float mx = logit;
#pragma unroll
            for (int m = 16; m >= 1; m >>= 1) mx = fmaxf(mx, __shfl_xor(mx, m, 32));
            float e = __expf(logit - mx);
            float se = e;
#pragma unroll
            for (int m = 16; m >= 1; m >>= 1) se += __shfl_xor(se, m, 32);
            wout[(size_t)(tok0 + tr) * NVAR + t] = e / se;
        }
    }
}

// ---------------- per-variable GRNs via MFMA, 8 n per block, reg-accumulated ----------------
// (UNCHANGED from round 4 — verified passing)
// grid (128 token-tiles, 4 n-groups), block 256 (4 waves), TT=64.
// LDS pool 61440 B (ushort units) — VG does NOT overlay EB:
//   VSB  [64][136] @ 0       EB  [64][72]  @ 8704
//   VH2B [64][136] @ 13312   VHB [64][136] @ 22016
//   VG   [64][264] @ 13312   (overlays dead VH2B+VHB only)
__global__ __launch_bounds__(256, 2) void k_var(
        const float* __restrict__ emb,
        const unsigned short* __restrict__ pk1, const unsigned short* __restrict__ pksk,
        const unsigned short* __restrict__ pk2, const unsigned short* __restrict__ pkg,
        const float* __restrict__ vb1, const float* __restrict__ vbsk,
        const float* __restrict__ vb2, const float* __restrict__ vbg,
        const float* __restrict__ gam, const float* __restrict__ bet,
        const float* __restrict__ wsel, float* __restrict__ outp) {
    __shared__ __align__(16) unsigned short pool[30720];
    unsigned short* VSB  = pool;
    unsigned short* EB   = pool + 8704;
    unsigned short* VH2B = pool + 13312;
    unsigned short* VHB  = pool + 22016;
    unsigned short* VG   = pool + 13312;

    const int tid = threadIdx.x;
    const int lane = tid & 63;
    const int w = tid >> 6;
    const int lr = lane & 15;
    const int lk = lane >> 4;
    const int tok0 = blockIdx.x * TT;
    const int gbase = blockIdx.y * 8;

    float accO[16][2];
#pragma unroll
    for (int i = 0; i < 16; ++i) { accO[i][0] = 0.f; accO[i][1] = 0.f; }

    for (int nn = 0; nn < 8; ++nn) {
        const int n = gbase + nn;

        // ---- stage E tile [64 tok][64] fp32 -> bf16 LDS ----
        {
            int row = tid >> 2, c0 = (tid & 3) * 16;
            const float* src = emb + ((size_t)(tok0 + row) * NVAR + n) * DDIM + c0;
            unsigned short* dst = EB + row * 72 + c0;
#pragma unroll
            for (int q = 0; q < 4; ++q) {
                float4 v = *(const float4*)(src + q * 4);
                dst[q * 4 + 0] = f2bf(v.x); dst[q * 4 + 1] = f2bf(v.y);
                dst[q * 4 + 2] = f2bf(v.z); dst[q * 4 + 3] = f2bf(v.w);
            }
        }
        __syncthreads();

        // ---- phase 1: VH = elu(E@W1+b1), VS = E@Wsk+bsk ----
        {
            f32x4 c1[4][2] = {};
            f32x4 c2[4][2] = {};
#pragma unroll
            for (int ks = 0; ks < 2; ++ks) {
                s16x8 af[4];
#pragma unroll
                for (int mf = 0; mf < 4; ++mf)
                    af[mf] = frag_ld(EB + (mf * 16 + lr) * 72 + ks * 32 + lk * 8);
                const unsigned short* p1 = pk1 + (size_t)n * 8192 + ((size_t)(ks * 8 + w * 2) * 64 + lane) * 8;
                const unsigned short* ps = pksk + (size_t)n * 8192 + ((size_t)(ks * 8 + w * 2) * 64 + lane) * 8;
                s16x8 b10 = frag_ld(p1), b11 = frag_ld(p1 + 512);
                s16x8 bs0 = frag_ld(ps), bs1 = frag_ld(ps + 512);
#pragma unroll
                for (int mf = 0; mf < 4; ++mf) {
                    c1[mf][0] = mfma_bf16(af[mf], b10, c1[mf][0]);
                    c1[mf][1] = mfma_bf16(af[mf], b11, c1[mf][1]);
                    c2[mf][0] = mfma_bf16(af[mf], bs0, c2[mf][0]);
                    c2[mf][1] = mfma_bf16(af[mf], bs1, c2[mf][1]);
                }
            }
#pragma unroll
            for (int nf = 0; nf < 2; ++nf) {
                int col = w * 32 + nf * 16 + lr;
                float bb1 = vb1[n * HDIM + col];
                float bbs = vbsk[n * HDIM + col];
#pragma unroll
                for (int mf = 0; mf < 4; ++mf)
#pragma unroll
                    for (int r = 0; r < 4; ++r) {
                        int row = mf * 16 + lk * 4 + r;
                        VHB[row * 136 + col] = f2bf(elu_f(c1[mf][nf][r] + bb1));
                        VSB[row * 136 + col] = f2bf(c2[mf][nf][r] + bbs);
                    }
            }
        }
        __syncthreads();

        // ---- phase 2: VH2 = VH@W2+b2 ----
        {
            f32x4 c3[4][2] = {};
#pragma unroll
            for (int ks = 0; ks < 4; ++ks) {
                s16x8 af[4];
#pragma unroll
                for (int mf = 0; mf < 4; ++mf)
                    af[mf] = frag_ld(VHB + (mf * 16 + lr) * 136 + ks * 32 + lk * 8);
                const unsigned short* p2 = pk2 + (size_t)n * 16384 + ((size_t)(ks * 8 + w * 2) * 64 + lane) * 8;
                s16x8 b0 = frag_ld(p2), b1 = frag_ld(p2 + 512);
#pragma unroll
                for (int mf = 0; mf < 4; ++mf) {
                    c3[mf][0] = mfma_bf16(af[mf], b0, c3[mf][0]);
                    c3[mf][1] = mfma_bf16(af[mf], b1, c3[mf][1]);
                }
            }
#pragma unroll
            for (int nf = 0; nf < 2; ++nf) {
                int col = w * 32 + nf * 16 + lr;
                float bb = vb2[n * HDIM + col];
#pragma unroll
                for (int mf = 0; mf < 4; ++mf)
#pragma unroll
                    for (int r = 0; r < 4; ++r)
                        VH2B[(mf * 16 + lk * 4 + r) * 136 + col] = f2bf(c3[mf][nf][r] + bb);
            }
        }
        __syncthreads();

        // ---- phase 3: VG = VH2@Wg+bg ----
        {
            f32x4 c4[4][4] = {};
#pragma unroll
            for (int ks = 0; ks < 4; ++ks) {
                s16x8 af[4];
#pragma unroll
                for (int mf = 0; mf < 4; ++mf)
                    af[mf] = frag_ld(VH2B + (mf * 16 + lr) * 136 + ks * 32 + lk * 8);
                const unsigned short* pg = pkg + (size_t)n * 32768 + ((size_t)(ks * 16 + w * 4) * 64 + lane) * 8;
#pragma unroll
                for (int nf = 0; nf < 4; ++nf) {
                    s16x8 bg = frag_ld(pg + nf * 512);
#pragma unroll
                    for (int mf = 0; mf < 4; ++mf)
                        c4[mf][nf] = mfma_bf16(af[mf], bg, c4[mf][nf]);
                }
            }
            __syncthreads();   // all VH2B reads done before VG overlays VH2B/VHB
#pragma unroll
            for (int nf = 0; nf < 4; ++nf) {
                int col = w * 64 + nf * 16 + lr;
                float bb = vbg[n * 256 + col];
#pragma unroll
                for (int mf = 0; mf < 4; ++mf)
#pragma unroll
                    for (int r = 0; r < 4; ++r)
                        VG[(mf * 16 + lk * 4 + r) * 264 + col] = f2bf(c4[mf][nf][r] + bb);
            }
        }
        __syncthreads();

        // ---- combine: glu + vskip, LN, *gamma+beta, *weight, accumulate in regs ----
        {
            int c0 = lane * 2;
            float g0 = gam[n * HDIM + c0], g1 = gam[n * HDIM + c0 + 1];
            float be0 = bet[n * HDIM + c0], be1 = bet[n * HDIM + c0 + 1];
#pragma unroll 2
            for (int i = 0; i < 16; ++i) {
                int tr = w * 16 + i;
                float a0 = bf2f(VG[tr * 264 + c0]);
                float a1v = bf2f(VG[tr * 264 + c0 + 1]);
                float b0 = bf2f(VG[tr * 264 + 128 + c0]);
                float b1v = bf2f(VG[tr * 264 + 128 + c0 + 1]);
                float s0 = bf2f(VSB[tr * 136 + c0]);
                float s1 = bf2f(VSB[tr * 136 + c0 + 1]);
                float v0 = a0 * sigm_f(b0) + s0;
                float v1 = a1v * sigm_f(b1v) + s1;
                float s = v0 + v1, q = v0 * v0 + v1 * v1;
#pragma unroll
                for (int m = 32; m >= 1; m >>= 1) { s += __shfl_xor(s, m); q += __shfl_xor(q, m); }
                float mean = s * (1.f / 128.f);
                float var = q * (1.f / 128.f) - mean * mean;
                float inv = rsqrtf(var + LN_EPS);
                float t0 = (v0 - mean) * inv * g0 + be0;
                float t1 = (v1 - mean) * inv * g1 + be1;
                float wgt = wsel[(size_t)(tok0 + tr) * NVAR + n];
                accO[i][0] += wgt * t0;
                accO[i][1] += wgt * t1;
            }
        }
        __syncthreads();   // combine reads done before next iteration's writes
    }

    // ---- one atomic per element per n-group ----
    {
        int c0 = lane * 2;
#pragma unroll
        for (int i = 0; i < 16; ++i) {
            float* po = outp + (size_t)(tok0 + w * 16 + i) * HDIM + c0;
            atomicAdd(po, accO[i][0]);
            atomicAdd(po + 1, accO[i][1]);
        }
    }
}

extern "C" void kernel_launch(void* const* d_in, const int* in_sizes, int n_in,
                              void* d_out, int out_size, void* d_ws, size_t ws_size,
                              hipStream_t stream) {
    const float* emb  = (const float*)d_in[0];
    const float* ctx  = (const float*)d_in[1];
    const float* fWsk = (const float*)d_in[2];
    const float* fbsk = (const float*)d_in[3];
    const float* fW1  = (const float*)d_in[4];
    const float* fb1  = (const float*)d_in[5];
    const float* fWc  = (const float*)d_in[6];
    const float* fW2  = (const float*)d_in[7];
    const float* fb2  = (const float*)d_in[8];
    const float* fWg  = (const float*)d_in[9];
    const float* fbg  = (const float*)d_in[10];
    const float* fg   = (const float*)d_in[11];
    const float* fb   = (const float*)d_in[12];
    const float* vWsk = (const float*)d_in[13];
    const float* vbsk = (const float*)d_in[14];
    const float* vW1  = (const float*)d_in[15];
    const float* vb1  = (const float*)d_in[16];
    const float* vW2  = (const float*)d_in[17];
    const float* vb2  = (const float*)d_in[18];
    const float* vWg  = (const float*)d_in[19];
    const float* vbg  = (const float*)d_in[20];
    const float* vgam = (const float*)d_in[21];
    const float* vbet = (const float*)d_in[22];

    float* outp = (float*)d_out;                       // [8192][128]
    float* wout = outp + (size_t)TOK * HDIM;           // [8192][32]

    // ---- workspace layout ----
    float* ctxp = (float*)d_ws;                        // [64][128]
    float* skip = ctxp + 64 * HDIM;                    // [8192][32] f32
    unsigned short* h1b  = (unsigned short*)(skip + (size_t)TOK * NVAR);  // [8192][128] bf16
    unsigned short* pk1  = h1b + (size_t)TOK * HDIM;   // [32][64][128]
    unsigned short* pksk = pk1 + 262144;               // [32][64][128]
    unsigned short* pk2  = pksk + 262144;              // [32][128][128]
    unsigned short* pkg  = pk2 + 524288;               // [32][128][256]
    unsigned short* pfW1 = pkg + 1048576;              // [2048][128] frag-packed
    unsigned short* pfWsk= pfW1 + 262144;              // [2048][32]
    unsigned short* pfW2 = pfWsk + 65536;              // [128][128]
    unsigned short* pfWg = pfW2 + 16384;               // [128][64]

    hipMemsetAsync(d_out, 0, (size_t)TOK * HDIM * sizeof(float), stream);
    // per-variable weight packs
    k_pack<<<dim3(16, 32), 64, 0, stream>>>(vW1, pk1, DDIM, HDIM);
    k_pack<<<dim3(16, 32), 64, 0, stream>>>(vWsk, pksk, DDIM, HDIM);
    k_pack<<<dim3(32, 32), 64, 0, stream>>>(vW2, pk2, HDIM, HDIM);
    k_pack<<<dim3(64, 32), 64, 0, stream>>>(vWg, pkg, HDIM, 2 * HDIM);
    // flatten weight packs
    k_pack<<<dim3(512, 1), 64, 0, stream>>>(fW1, pfW1, ND, HDIM);
    k_pack<<<dim3(128, 1), 64, 0, stream>>>(fWsk, pfWsk, ND, NVAR);
    k_pack<<<dim3(32, 1), 64, 0, stream>>>(fW2, pfW2, HDIM, HDIM);
    k_pack<<<dim3(16, 1), 64, 0, stream>>>(fWg, pfWg, HDIM, 64);

    k_ctx<<<64, 128, 0, stream>>>(ctx, fWc, ctxp);
    k_flat<<<256, 128, 0, stream>>>(emb, pfW1, pfWsk, fb1, fbsk, ctxp, h1b, skip);
    k_sel<<<256, 128, 0, stream>>>(h1b, skip, pfW2, fb2, pfWg, fbg, fg, fb, wout);
    k_var<<<dim3(TOK / TT, 4), 256, 0, stream>>>(emb, pk1, pksk, pk2, pkg,
                                                 vb1, vbsk, vb2, vbg, vgam, vbet,
                                                 wout, outp);
}